// Round 3
// baseline (702.649 us; speedup 1.0000x reference)
//
#include <hip/hip_runtime.h>

#define Mdim 4096
#define Kdim 4096
#define Ndim 12288

typedef __bf16 bf16x8 __attribute__((ext_vector_type(8)));
typedef float f32x4 __attribute__((ext_vector_type(4)));
typedef unsigned short u16x8 __attribute__((ext_vector_type(8)));
typedef int i32x4 __attribute__((ext_vector_type(4)));

__device__ __forceinline__ unsigned short f2bf(float f) {
    unsigned int u = __builtin_bit_cast(unsigned int, f);
    u += 0x7FFFu + ((u >> 16) & 1u);       // RNE
    return (unsigned short)(u >> 16);
}

typedef __attribute__((address_space(1))) void gvoid_t;
typedef __attribute__((address_space(3))) void lvoid_t;
__device__ __forceinline__ void gld16(const void* g, void* l) {
    // 16B per lane, LDS dest = wave-uniform base + lane*16
    __builtin_amdgcn_global_load_lds((gvoid_t*)g, (lvoid_t*)l, 16, 0, 0);
}

// ---------------------------------------------------------------------------
// Kernel 0: A fp32 -> bf16 with K-permutation folded in (unchanged).
// ---------------------------------------------------------------------------
__global__ __launch_bounds__(256) void permute_convert_a_kernel(
    const float* __restrict__ A, const int* __restrict__ invperm,
    unsigned short* __restrict__ Ab)
{
    __shared__ unsigned short rowbuf[2][Kdim];
    const int tid = threadIdx.x;
    const int m0 = blockIdx.x * 2;
#pragma unroll
    for (int c = 0; c < 4; ++c) {
        const int i = (c * 256 + tid) * 4;
        const i32x4 ip = *(const i32x4*)&invperm[i];
        const f32x4 v0 = *(const f32x4*)&A[(size_t)m0 * Kdim + i];
        const f32x4 v1 = *(const f32x4*)&A[(size_t)(m0 + 1) * Kdim + i];
#pragma unroll
        for (int u = 0; u < 4; ++u) {
            rowbuf[0][ip[u]] = f2bf(v0[u]);
            rowbuf[1][ip[u]] = f2bf(v1[u]);
        }
    }
    __syncthreads();
#pragma unroll
    for (int r = 0; r < 2; ++r)
#pragma unroll
        for (int c = 0; c < 2; ++c) {
            const int j = (c * 256 + tid) * 8;
            const u16x8 o = *(const u16x8*)&rowbuf[r][j];
            *(u16x8*)&Ab[(size_t)(m0 + r) * Kdim + j] = o;
        }
}

// ---------------------------------------------------------------------------
// Kernel 1: dequant in natural k-order (unchanged).
// ---------------------------------------------------------------------------
__global__ __launch_bounds__(256) void dequant_kernel(
    const int* __restrict__ qw,              // [K/8][N]
    const int* __restrict__ qs,              // [G][N/8]
    const float* __restrict__ qsm,           // [G] fp32
    unsigned short* __restrict__ Wt)         // [N][K] bf16 bits
{
    __shared__ unsigned short tile[64 * 72];
    const int k0 = blockIdx.x * 64;
    const int n0 = blockIdx.y * 64;
    const int g = k0 >> 7;
    const int tid = threadIdx.x;
    const int n_l = tid & 63;
    const int kb_l = tid >> 6;
    const int n = n0 + n_l;
    const int sw = qs[g * (Ndim / 8) + (n >> 3)];
    const int sc = (sw >> ((n & 7) * 4)) & 0xF;
    const float scale = (float)((sc + 1) * (sc + 1)) * qsm[g];
#pragma unroll
    for (int ii = 0; ii < 2; ++ii) {
        const int kb = kb_l + ii * 4;
        const int w = qw[(size_t)(k0 / 8 + kb) * Ndim + n];
        u16x8 o;
#pragma unroll
        for (int u = 0; u < 8; ++u)
            o[u] = f2bf((float)(((w >> (4 * u)) & 0xF) - 8) * scale);
        *(u16x8*)&tile[n_l * 72 + kb * 8] = o;
    }
    __syncthreads();
#pragma unroll
    for (int cc = 0; cc < 2; ++cc) {
        const int c = tid + cc * 256;
        const int row = c >> 3, part = c & 7;
        const u16x8 v = *(const u16x8*)&tile[row * 72 + part * 8];
        *(u16x8*)&Wt[(size_t)(n0 + row) * Kdim + k0 + part * 8] = v;
    }
}

// ---------------------------------------------------------------------------
// Kernel 2: bf16 GEMM, 256x256 tile, BK=64, 8 waves, 4-phase/K-tile schedule
// with counted vmcnt (unchanged schedule from round 2).
//
// NEW: LDS in MFMA-FRAGMENT ORDER (replaces the failed chunk-XOR swizzle,
// which left bank = 16*(row&1)+4*chunk -> structural 4-way conflict,
// SQ_LDS_BANK_CONFLICT=3.78e7 = +4 cyc per b128).
// A K-half region (256 rows x 32 halves, 16 KiB) = 16 blocks of 16 rows.
// Block q stores chunk l (16B) = logical (row 16q+(l&15), k-halves (l>>4)*8)
// at halves q*512 + l*8.  Every fragment ds_read_b128 is then a wave reading
// 1024 CONSECUTIVE bytes (base + lane*16) -- identical shape to the
// global_load_lds writes, conflict-free under any bank-grouping model.
// Staging pre-permutes the GLOBAL source instead: wave w, gld g covers block
// g*8+w; lane l loads row 16w+(l&15) (+128 for g=1), k-chunk (l>>4)*8.
// Same 64B-per-row coalescing granularity as before; address math is simpler
// (no XOR).  Ring slots, vmcnt schedule, barriers, setprio all unchanged.
// ---------------------------------------------------------------------------
#define BAR()    asm volatile("s_barrier" ::: "memory")
#define VMCNT8() asm volatile("s_waitcnt vmcnt(8)" ::: "memory")

#define STAGE(dstW, src, slot, koff) do {                                   \
    gld16((src) + (koff), (dstW) + (slot) * 8192);                          \
    gld16((src) + (koff) + rstep, (dstW) + (slot) * 8192 + 4096); } while (0)

#define LD_A(slot, mh) do {                                                 \
    const unsigned short* p_ = &As[slot][wm * 4096 + (mh) * 2048 + aOff];   \
    af[0] = *(const bf16x8*)(p_);                                           \
    af[1] = *(const bf16x8*)(p_ + 512);                                     \
    af[2] = *(const bf16x8*)(p_ + 1024);                                    \
    af[3] = *(const bf16x8*)(p_ + 1536); } while (0)

#define LD_B(slot) do {                                                     \
    const unsigned short* p_ = &Bs[slot][wn * 2048 + aOff];                 \
    bf[0] = *(const bf16x8*)(p_);                                           \
    bf[1] = *(const bf16x8*)(p_ + 512);                                     \
    bf[2] = *(const bf16x8*)(p_ + 1024);                                    \
    bf[3] = *(const bf16x8*)(p_ + 1536); } while (0)

#define MFMA_HALF(mh) do {                                                  \
    __builtin_amdgcn_s_setprio(1);                                          \
    _Pragma("unroll")                                                       \
    for (int i_ = 0; i_ < 4; ++i_)                                          \
      _Pragma("unroll")                                                     \
      for (int j_ = 0; j_ < 4; ++j_)                                        \
        acc[(mh) * 4 + i_][j_] = __builtin_amdgcn_mfma_f32_16x16x32_bf16(   \
            af[i_], bf[j_], acc[(mh) * 4 + i_][j_], 0, 0, 0);               \
    __builtin_amdgcn_s_setprio(0); } while (0)

__global__ __launch_bounds__(512, 2) void gemm_bf16_256_kernel(
    const unsigned short* __restrict__ A,    // x-permuted [M][K] bf16 bits
    const unsigned short* __restrict__ Bt,   // Wt [N][K] bf16 bits
    const float* __restrict__ bias,          // [N] fp32
    float* __restrict__ C)                   // [M][N] fp32
{
    __shared__ __attribute__((aligned(16))) unsigned short As[4][8192];
    __shared__ __attribute__((aligned(16))) unsigned short Bs[4][8192];

    const int tid = threadIdx.x;
    const int lane = tid & 63, wave = tid >> 6;
    const int wm = wave >> 2, wn = wave & 3;

    // bijective XCD swizzle: 768 wgs = 8 XCDs x 96. Chunk spans all 16 bm x
    // 6 bn -> each B panel L2-resident per XCD, A panels recycle via L3.
    const int wgid = (blockIdx.x & 7) * 96 + (blockIdx.x >> 3);
    const int bm = wgid & 15;    // 0..15  (M/256)
    const int bn = wgid >> 4;    // 0..47  (N/256)

    // ---- staging source (fragment-order): wave w, gld g -> block g*8+w;
    //      lane l -> row 16w+(l&15) (+128 if g=1), k-chunk (l>>4)*8 ----
    const int srow = 16 * wave + (lane & 15);
    const int skoff = (lane >> 4) * 8;
    const unsigned short* Ag = A + (size_t)(bm * 256 + srow) * Kdim + skoff;
    const unsigned short* Bg = Bt + (size_t)(bn * 256 + srow) * Kdim + skoff;
    const size_t rstep = (size_t)128 * Kdim;
    unsigned short* AsW = &As[0][0] + wave * 512;   // wave-uniform dest base
    unsigned short* BsW = &Bs[0][0] + wave * 512;

    // ---- fragment read offset: contiguous, lane*16B within block ----
    const int aOff = lane * 8;

    f32x4 acc[8][4];
    const f32x4 zero = {0.f, 0.f, 0.f, 0.f};
#pragma unroll
    for (int i = 0; i < 8; ++i)
#pragma unroll
        for (int j = 0; j < 4; ++j) acc[i][j] = zero;

    // ---- prologue: A0(0) B0(0) A1(0) B1(0) A0(1) B0(1); drain first 4 ----
    STAGE(AsW, Ag, 0, 0);
    STAGE(BsW, Bg, 0, 0);
    STAGE(AsW, Ag, 1, 32);
    STAGE(BsW, Bg, 1, 32);
    STAGE(AsW, Ag, 2, 64);
    STAGE(BsW, Bg, 2, 64);
    VMCNT8();
    BAR();

    bf16x8 af[4], bf[4];
#pragma unroll 2
    for (int t = 0; t < 64; ++t) {
        const int s0 = (2 * t) & 3, s1 = (2 * t + 1) & 3, sd1 = (2 * t + 3) & 3;
        const int tn1 = (t + 1 < 64 ? t + 1 : 63) * 64;
        const int tn2 = (t + 2 < 64 ? t + 2 : 63) * 64;
        // P1: kstep0, M-half0
        LD_A(s0, 0);
        LD_B(s0);
        STAGE(AsW, Ag, sd1, tn1 + 32);
        BAR();
        MFMA_HALF(0);
        BAR();
        // P2: kstep0, M-half1 (bf reused)
        LD_A(s0, 1);
        STAGE(BsW, Bg, sd1, tn1 + 32);
        VMCNT8();                      // completes A-Kh1(t), B-Kh1(t)
        BAR();
        MFMA_HALF(1);
        BAR();
        // P3: kstep1, M-half0
        LD_A(s1, 0);
        LD_B(s1);
        STAGE(AsW, Ag, s0, tn2);       // overwrite kstep0 slot (reads done P2)
        BAR();
        MFMA_HALF(0);
        BAR();
        // P4: kstep1, M-half1
        LD_A(s1, 1);
        STAGE(BsW, Bg, s0, tn2);
        VMCNT8();                      // completes A-Kh0(t+1), B-Kh0(t+1)
        BAR();
        MFMA_HALF(1);
        BAR();
    }

    // ---- epilogue: C/D layout col = lane&15, row = (lane>>4)*4 + r ----
    const int colb = bn * 256 + wn * 64 + (lane & 15);
    const int rowb = bm * 256 + wm * 128 + (lane >> 4) * 4;
    float bj[4];
#pragma unroll
    for (int j = 0; j < 4; ++j) bj[j] = bias[colb + j * 16];
#pragma unroll
    for (int mf = 0; mf < 8; ++mf)
#pragma unroll
        for (int r = 0; r < 4; ++r) {
            const size_t row = (size_t)(rowb + mf * 16 + r);
#pragma unroll
            for (int j = 0; j < 4; ++j)
                C[row * Ndim + colb + j * 16] = acc[mf][j][r] + bj[j];
        }
}

extern "C" void kernel_launch(void* const* d_in, const int* in_sizes, int n_in,
                              void* d_out, int out_size, void* d_ws, size_t ws_size,
                              hipStream_t stream) {
    const float* input   = (const float*)d_in[0];   // [M][K] fp32 (fp16 promoted)
    const int*   qw      = (const int*)d_in[1];     // [K/8][N]
    const int*   qs      = (const int*)d_in[2];     // [G][N/8]
    const float* qsm     = (const float*)d_in[3];   // [G] fp32
    const int*   invperm = (const int*)d_in[4];     // [K]
    const float* bias    = (const float*)d_in[5];   // [N] fp32 (zeros)
    float*       out     = (float*)d_out;           // [M][N] fp32

    unsigned short* Ab = (unsigned short*)d_ws;                      // 32 MiB
    unsigned short* Wt = (unsigned short*)((char*)d_ws + ((size_t)Mdim * Kdim * 2)); // 96 MiB

    permute_convert_a_kernel<<<Mdim / 2, 256, 0, stream>>>(input, invperm, Ab);
    dequant_kernel<<<dim3(Kdim / 64, Ndim / 64), 256, 0, stream>>>(qw, qs, qsm, Wt);
    gemm_bf16_256_kernel<<<dim3((Mdim / 256) * (Ndim / 256)), 512, 0, stream>>>(
        Ab, Wt, bias, out);
}

// Round 4
// 600.266 us; speedup vs baseline: 1.1706x; 1.1706x over previous
//
#include <hip/hip_runtime.h>

#define Mdim 4096
#define Kdim 4096
#define Ndim 12288

typedef __bf16 bf16x8 __attribute__((ext_vector_type(8)));
typedef float f32x4 __attribute__((ext_vector_type(4)));
typedef unsigned short u16x8 __attribute__((ext_vector_type(8)));
typedef int i32x4 __attribute__((ext_vector_type(4)));

__device__ __forceinline__ unsigned short f2bf(float f) {
    unsigned int u = __builtin_bit_cast(unsigned int, f);
    u += 0x7FFFu + ((u >> 16) & 1u);       // RNE
    return (unsigned short)(u >> 16);
}

typedef __attribute__((address_space(1))) void gvoid_t;
typedef __attribute__((address_space(3))) void lvoid_t;
__device__ __forceinline__ void gld16(const void* g, void* l) {
    // 16B per lane, LDS dest = wave-uniform base + lane*16
    __builtin_amdgcn_global_load_lds((gvoid_t*)g, (lvoid_t*)l, 16, 0, 0);
}

// ---------------------------------------------------------------------------
// TILED OPERAND FORMAT (fragment order), shared by writer kernels and GEMM.
// For a 256-row operand tile bx (bm or bn), element (row, k):
//   ks = k>>5 (region, 8192 halves), kk = k&31, q = row>>4 (512-half block),
//   chunk l = (row&15) + 16*(kk>>3)   (16B chunks, MFMA-fragment order)
//   addr_halves = bx*2^20 + ks*8192 + q*512 + l*8 + (kk&7)
// GEMM staging then reads 1KB fully-contiguous per wave-instr (perfect
// coalescing) AND the LDS image gives fully-sequential fragment ds_reads
// (round-3-proven 0 bank conflicts).  This resolves the r2/r3 tension:
// with global_load_lds (linear LDS write in lane order) you cannot have
// both a coalesced source and a conflict-free fragment read unless the
// GLOBAL layout itself is fragment-ordered -- we own the writers, so it is.
// ---------------------------------------------------------------------------

// ---------------------------------------------------------------------------
// Kernel 0: A fp32 -> bf16, K-permutation folded in, TILED output.
// 16 rows (one q-block) per workgroup, full K rows staged in LDS so the
// invperm scatter stays local; output written as contiguous 1KB sub-blocks.
// ---------------------------------------------------------------------------
__global__ __launch_bounds__(512) void permute_convert_a_kernel(
    const float* __restrict__ A, const int* __restrict__ invperm,
    unsigned short* __restrict__ Ab)
{
    __shared__ unsigned short rowbuf[16][4104];   // +16B row pad (bank spread)
    const int tid = threadIdx.x;
    const int m0 = blockIdx.x * 16;
    const int bm = m0 >> 8;
    const int q  = (m0 >> 4) & 15;
#pragma unroll
    for (int c = 0; c < 2; ++c) {
        const int i = (c * 512 + tid) * 4;
        const i32x4 ip = *(const i32x4*)&invperm[i];
        for (int r = 0; r < 16; ++r) {
            const f32x4 v = *(const f32x4*)&A[(size_t)(m0 + r) * Kdim + i];
#pragma unroll
            for (int u = 0; u < 4; ++u) rowbuf[r][ip[u]] = f2bf(v[u]);
        }
    }
    __syncthreads();
    unsigned short* dst = Ab + ((size_t)bm << 20) + q * 512;
    for (int it = 0; it < 16; ++it) {
        const int c = it * 512 + tid;             // 0..8191
        const int ks = c >> 6, c8 = c & 63;
        const u16x8 v = *(const u16x8*)&rowbuf[c8 & 15][ks * 32 + (c8 >> 4) * 8];
        *(u16x8*)&dst[(size_t)ks * 8192 + c8 * 8] = v;   // 1KB contig / 64 thr
    }
}

// ---------------------------------------------------------------------------
// Kernel 1: dequant in natural k-order; compute unchanged, TILED output.
// Block tile 64k x 64n = 2 regions x 4 q-blocks; each (ks,q) sub-block is a
// contiguous 1KB write.
// ---------------------------------------------------------------------------
__global__ __launch_bounds__(256) void dequant_kernel(
    const int* __restrict__ qw,              // [K/8][N]
    const int* __restrict__ qs,              // [G][N/8]
    const float* __restrict__ qsm,           // [G] fp32
    unsigned short* __restrict__ Wt)         // tiled bf16 bits
{
    __shared__ unsigned short tile[64 * 72];
    const int k0 = blockIdx.x * 64;
    const int n0 = blockIdx.y * 64;
    const int g = k0 >> 7;
    const int tid = threadIdx.x;
    const int n_l = tid & 63;
    const int kb_l = tid >> 6;
    const int n = n0 + n_l;
    const int sw = qs[g * (Ndim / 8) + (n >> 3)];
    const int sc = (sw >> ((n & 7) * 4)) & 0xF;
    const float scale = (float)((sc + 1) * (sc + 1)) * qsm[g];
#pragma unroll
    for (int ii = 0; ii < 2; ++ii) {
        const int kb = kb_l + ii * 4;
        const int w = qw[(size_t)(k0 / 8 + kb) * Ndim + n];
        u16x8 o;
#pragma unroll
        for (int u = 0; u < 8; ++u)
            o[u] = f2bf((float)(((w >> (4 * u)) & 0xF) - 8) * scale);
        *(u16x8*)&tile[n_l * 72 + kb * 8] = o;
    }
    __syncthreads();
    const int bn  = n0 >> 8;
    const int q0  = (n0 >> 4) & 15;
    const int ks0 = k0 >> 5;
    unsigned short* dst = Wt + ((size_t)bn << 20) + (size_t)ks0 * 8192 + q0 * 512;
#pragma unroll
    for (int cc = 0; cc < 2; ++cc) {
        const int c  = cc * 256 + tid;            // 0..511
        const int ksl = c >> 8;                   // 0..1
        const int cq  = (c >> 6) & 3;             // q-block within our 64n
        const int c8  = c & 63;
        const u16x8 v = *(const u16x8*)
            &tile[(cq * 16 + (c8 & 15)) * 72 + ksl * 32 + (c8 >> 4) * 8];
        *(u16x8*)&dst[(size_t)ksl * 8192 + cq * 512 + c8 * 8] = v;
    }
}

// ---------------------------------------------------------------------------
// Kernel 2: bf16 GEMM, 256x256 tile, BK=64, 8 waves, 4-phase/K-tile schedule
// with counted vmcnt (schedule unchanged from rounds 2-3).
// Operands are pre-tiled (see format above): staging thread t reads global
// base + R*8192 + t*16B -- every wave-instr is 1KB contiguous; LDS image is
// fragment-order so every frag ds_read_b128 is a wave reading 1024
// consecutive bytes (0 bank conflicts, round-3-verified).
// Ring: 4 slots/operand of one region (16KB); region R consumed at tile
// t=R>>1, kstep R&1; staged 5-7 phases ahead; VMCNT8 (12 outstanding -> 8)
// retires exactly the 2 regions read next.
// ---------------------------------------------------------------------------
#define BAR()    asm volatile("s_barrier" ::: "memory")
#define VMCNT8() asm volatile("s_waitcnt vmcnt(8)" ::: "memory")

#define STAGE(dstW, src, slot, R) do {                                      \
    gld16((src) + (size_t)(R) * 8192, (dstW) + (slot) * 8192);              \
    gld16((src) + (size_t)(R) * 8192 + 4096,                                \
          (dstW) + (slot) * 8192 + 4096); } while (0)

#define LD_A(slot, mh) do {                                                 \
    const unsigned short* p_ = &As[slot][wm * 4096 + (mh) * 2048 + aOff];   \
    af[0] = *(const bf16x8*)(p_);                                           \
    af[1] = *(const bf16x8*)(p_ + 512);                                     \
    af[2] = *(const bf16x8*)(p_ + 1024);                                    \
    af[3] = *(const bf16x8*)(p_ + 1536); } while (0)

#define LD_B(slot) do {                                                     \
    const unsigned short* p_ = &Bs[slot][wn * 2048 + aOff];                 \
    bf[0] = *(const bf16x8*)(p_);                                           \
    bf[1] = *(const bf16x8*)(p_ + 512);                                     \
    bf[2] = *(const bf16x8*)(p_ + 1024);                                    \
    bf[3] = *(const bf16x8*)(p_ + 1536); } while (0)

#define MFMA_HALF(mh) do {                                                  \
    __builtin_amdgcn_s_setprio(1);                                          \
    _Pragma("unroll")                                                       \
    for (int i_ = 0; i_ < 4; ++i_)                                          \
      _Pragma("unroll")                                                     \
      for (int j_ = 0; j_ < 4; ++j_)                                        \
        acc[(mh) * 4 + i_][j_] = __builtin_amdgcn_mfma_f32_16x16x32_bf16(   \
            af[i_], bf[j_], acc[(mh) * 4 + i_][j_], 0, 0, 0);               \
    __builtin_amdgcn_s_setprio(0); } while (0)

__global__ __launch_bounds__(512, 2) void gemm_bf16_256_kernel(
    const unsigned short* __restrict__ A,    // tiled [M-tiles] bf16 bits
    const unsigned short* __restrict__ Bt,   // tiled [N-tiles] bf16 bits
    const float* __restrict__ bias,          // [N] fp32
    float* __restrict__ C)                   // [M][N] fp32
{
    __shared__ __attribute__((aligned(16))) unsigned short As[4][8192];
    __shared__ __attribute__((aligned(16))) unsigned short Bs[4][8192];

    const int tid = threadIdx.x;
    const int lane = tid & 63, wave = tid >> 6;
    const int wm = wave >> 2, wn = wave & 3;

    // bijective XCD swizzle: 768 wgs = 8 XCDs x 96.
    const int wgid = (blockIdx.x & 7) * 96 + (blockIdx.x >> 3);
    const int bm = wgid & 15;    // 0..15  (M/256)
    const int bn = wgid >> 4;    // 0..47  (N/256)

    // ---- staging: pure linear stream; thread t covers bytes t*16 ----
    const unsigned short* Ag = A + ((size_t)bm << 20) + tid * 8;
    const unsigned short* Bg = Bt + ((size_t)bn << 20) + tid * 8;
    unsigned short* AsW = &As[0][0] + wave * 512;   // wave-uniform dest base
    unsigned short* BsW = &Bs[0][0] + wave * 512;

    // ---- fragment read offset: contiguous, lane*16B within q-block ----
    const int aOff = lane * 8;

    f32x4 acc[8][4];
    const f32x4 zero = {0.f, 0.f, 0.f, 0.f};
#pragma unroll
    for (int i = 0; i < 8; ++i)
#pragma unroll
        for (int j = 0; j < 4; ++j) acc[i][j] = zero;

    // ---- prologue: regions 0,1,2 of A and B; drain first 4 of 12 ----
    STAGE(AsW, Ag, 0, 0);
    STAGE(BsW, Bg, 0, 0);
    STAGE(AsW, Ag, 1, 1);
    STAGE(BsW, Bg, 1, 1);
    STAGE(AsW, Ag, 2, 2);
    STAGE(BsW, Bg, 2, 2);
    VMCNT8();
    BAR();

    bf16x8 af[4], bf[4];
#pragma unroll 2
    for (int t = 0; t < 64; ++t) {
        const int s0 = (2 * t) & 3, s1 = (2 * t + 1) & 3, sd1 = (2 * t + 3) & 3;
        const int R1 = (2 * t + 3 < 128) ? (2 * t + 3) : 127;
        const int R2 = (2 * t + 4 < 128) ? (2 * t + 4) : 127;
        // P1: kstep0, M-half0
        LD_A(s0, 0);
        LD_B(s0);
        STAGE(AsW, Ag, sd1, R1);
        BAR();
        MFMA_HALF(0);
        BAR();
        // P2: kstep0, M-half1 (bf reused)
        LD_A(s0, 1);
        STAGE(BsW, Bg, sd1, R1);
        VMCNT8();                      // completes A,B region 2t+1
        BAR();
        MFMA_HALF(1);
        BAR();
        // P3: kstep1, M-half0
        LD_A(s1, 0);
        LD_B(s1);
        STAGE(AsW, Ag, s0, R2);        // overwrite kstep0 slot (reads done P2)
        BAR();
        MFMA_HALF(0);
        BAR();
        // P4: kstep1, M-half1
        LD_A(s1, 1);
        STAGE(BsW, Bg, s0, R2);
        VMCNT8();                      // completes A,B region 2t+2
        BAR();
        MFMA_HALF(1);
        BAR();
    }

    // ---- epilogue: C/D layout col = lane&15, row = (lane>>4)*4 + r ----
    const int colb = bn * 256 + wn * 64 + (lane & 15);
    const int rowb = bm * 256 + wm * 128 + (lane >> 4) * 4;
    float bj[4];
#pragma unroll
    for (int j = 0; j < 4; ++j) bj[j] = bias[colb + j * 16];
#pragma unroll
    for (int mf = 0; mf < 8; ++mf)
#pragma unroll
        for (int r = 0; r < 4; ++r) {
            const size_t row = (size_t)(rowb + mf * 16 + r);
#pragma unroll
            for (int j = 0; j < 4; ++j)
                C[row * Ndim + colb + j * 16] = acc[mf][j][r] + bj[j];
        }
}

extern "C" void kernel_launch(void* const* d_in, const int* in_sizes, int n_in,
                              void* d_out, int out_size, void* d_ws, size_t ws_size,
                              hipStream_t stream) {
    const float* input   = (const float*)d_in[0];   // [M][K] fp32 (fp16 promoted)
    const int*   qw      = (const int*)d_in[1];     // [K/8][N]
    const int*   qs      = (const int*)d_in[2];     // [G][N/8]
    const float* qsm     = (const float*)d_in[3];   // [G] fp32
    const int*   invperm = (const int*)d_in[4];     // [K]
    const float* bias    = (const float*)d_in[5];   // [N] fp32 (zeros)
    float*       out     = (float*)d_out;           // [M][N] fp32

    unsigned short* Ab = (unsigned short*)d_ws;                      // 32 MiB
    unsigned short* Wt = (unsigned short*)((char*)d_ws + ((size_t)Mdim * Kdim * 2)); // 96 MiB

    permute_convert_a_kernel<<<Mdim / 16, 512, 0, stream>>>(input, invperm, Ab);
    dequant_kernel<<<dim3(Kdim / 64, Ndim / 64), 256, 0, stream>>>(qw, qs, qsm, Wt);
    gemm_bf16_256_kernel<<<dim3((Mdim / 256) * (Ndim / 256)), 512, 0, stream>>>(
        Ab, Wt, bias, out);
}